// Round 2
// baseline (317.388 us; speedup 1.0000x reference)
//
#include <hip/hip_runtime.h>
#include <hip/hip_bf16.h>

#define N_NODES 20000
#define N_EDGES 320000
#define F_IN    128
#define F_HID   32
#define NHEAD   8
#define FDIM    256   // NHEAD * D for both layers

// ---------------- CSR build ----------------
__global__ void zero_kernel(int* __restrict__ p, int n){
  int i = blockIdx.x*256 + threadIdx.x;
  if (i < n) p[i] = 0;
}

__global__ void hist_kernel(const int* __restrict__ dst, int* __restrict__ cnt, int e){
  int i = blockIdx.x*256 + threadIdx.x;
  if (i < e) atomicAdd(&cnt[dst[i]], 1);
}

__global__ __launch_bounds__(1024) void scan_kernel(
    const int* __restrict__ cnt, int* __restrict__ rowptr,
    int* __restrict__ fillp, int n)
{
  __shared__ int wsum[16];
  __shared__ int carry_s;
  const int tid = threadIdx.x;
  if (tid == 0) carry_s = 0;
  __syncthreads();
  for (int base = 0; base < n; base += 1024){
    const int i = base + tid;
    const int v = (i < n) ? cnt[i] : 0;
    const int lane = tid & 63;
    const int w = tid >> 6;
    int sc = v;
    #pragma unroll
    for (int o = 1; o < 64; o <<= 1){
      int t = __shfl_up(sc, o);
      if (lane >= o) sc += t;
    }
    if (lane == 63) wsum[w] = sc;
    const int c = carry_s;           // read before this iter's update
    __syncthreads();
    if (tid < 16){
      int sv = wsum[tid];
      #pragma unroll
      for (int o = 1; o < 16; o <<= 1){
        int t = __shfl_up(sv, o);
        if (tid >= o) sv += t;
      }
      wsum[tid] = sv;                // inclusive scan of wave sums
    }
    __syncthreads();
    const int woff = (w > 0) ? wsum[w-1] : 0;
    const int excl = sc + woff + c - v;
    if (i < n){ rowptr[i] = excl; fillp[i] = excl; }
    __syncthreads();
    if (tid == 1023) carry_s = c + wsum[15];
    __syncthreads();
  }
  if (tid == 0) rowptr[n] = carry_s;
}

__global__ void fill_kernel(const int* __restrict__ src, const int* __restrict__ dst,
                            int* __restrict__ fillp, int* __restrict__ col, int e){
  int i = blockIdx.x*256 + threadIdx.x;
  if (i < e){
    int d = dst[i];
    int p = atomicAdd(&fillp[d], 1);
    col[p] = src[i];
  }
}

// ---------------- feat = x @ W ; el/er = head-dot with al/ar ----------------
// block = 256 threads (one thread per output column), 8 nodes per block.
template<int K>
__global__ __launch_bounds__(256) void gemm_aux_kernel(
    const float* __restrict__ x, const float* __restrict__ W,
    const float* __restrict__ al, const float* __restrict__ ar,
    float* __restrict__ feat, float* __restrict__ el, float* __restrict__ er)
{
  const int tid = threadIdx.x;
  const int n0  = blockIdx.x * 8;
  __shared__ float xl[8 * K];
  // vectorized stage of 8 rows of x into LDS
  #pragma unroll
  for (int i = tid; i < (8*K)/4; i += 256){
    ((float4*)xl)[i] = ((const float4*)(x + (size_t)n0*K))[i];
  }
  __syncthreads();
  float acc[8] = {0.f,0.f,0.f,0.f,0.f,0.f,0.f,0.f};
  for (int k = 0; k < K; k += 4){
    float w0 = W[(k+0)*FDIM + tid];
    float w1 = W[(k+1)*FDIM + tid];
    float w2 = W[(k+2)*FDIM + tid];
    float w3 = W[(k+3)*FDIM + tid];
    #pragma unroll
    for (int nn = 0; nn < 8; nn++){
      float4 xv = *(const float4*)&xl[nn*K + k];   // wave-uniform broadcast read
      acc[nn] = fmaf(xv.x, w0, acc[nn]);
      acc[nn] = fmaf(xv.y, w1, acc[nn]);
      acc[nn] = fmaf(xv.z, w2, acc[nn]);
      acc[nn] = fmaf(xv.w, w3, acc[nn]);
    }
  }
  const float alv = al[tid];
  const float arv = ar[tid];
  #pragma unroll
  for (int nn = 0; nn < 8; nn++){
    const int nidx = n0 + nn;
    feat[(size_t)nidx*FDIM + tid] = acc[nn];
    float e_l = acc[nn] * alv;
    float e_r = acc[nn] * arv;
    #pragma unroll
    for (int off = 16; off >= 1; off >>= 1){
      e_l += __shfl_xor(e_l, off);   // stays within the 32-lane head group
      e_r += __shfl_xor(e_r, off);
    }
    if ((tid & 31) == 0){
      el[nidx*NHEAD + (tid >> 5)] = e_l;
      er[nidx*NHEAD + (tid >> 5)] = e_r;
    }
  }
}

// ---------------- per-dst-node edge softmax + aggregate ----------------
// block = 256 threads: thread = (h = tid>>5, d = tid&31). One block per node.
template<int RELU_MEAN>
__global__ __launch_bounds__(256) void edge_agg_kernel(
    const float* __restrict__ feat, const float* __restrict__ el,
    const float* __restrict__ er, const int* __restrict__ rowptr,
    const int* __restrict__ col, const float* __restrict__ bias,
    float* __restrict__ outp)
{
  const int n   = blockIdx.x;
  const int tid = threadIdx.x;
  const int h   = tid >> 5;
  const int d   = tid & 31;
  __shared__ float t_lds[128*9];   // stride 9: conflict-free strided reads
  __shared__ int   srcs[128];
  __shared__ float er_lds[NHEAD];
  __shared__ float red[256];
  const int start = rowptr[n], end = rowptr[n+1];
  if (tid < NHEAD) er_lds[tid] = er[n*NHEAD + tid];
  __syncthreads();

  float m = -INFINITY, s = 0.f, acc = 0.f;
  for (int cs = start; cs < end; cs += 128){
    const int rem = end - cs;
    const int C = rem < 128 ? rem : 128;
    if (tid < C){
      const int sidx = col[cs + tid];
      srcs[tid] = sidx;
      const float4* e4 = (const float4*)(el + (size_t)sidx*NHEAD);
      float4 a = e4[0], bq = e4[1];
      float ev[8] = {a.x, a.y, a.z, a.w, bq.x, bq.y, bq.z, bq.w};
      #pragma unroll
      for (int hh = 0; hh < 8; hh++){
        float v = ev[hh] + er_lds[hh];
        t_lds[tid*9 + hh] = (v > 0.f) ? v : 0.2f*v;   // leaky_relu(0.2)
      }
    }
    __syncthreads();
    // chunk max per head (32-lane head group)
    float lm = -INFINITY;
    for (int e = d; e < C; e += 32) lm = fmaxf(lm, t_lds[e*9 + h]);
    #pragma unroll
    for (int off = 16; off >= 1; off >>= 1) lm = fmaxf(lm, __shfl_xor(lm, off));
    const float newm = fmaxf(m, lm);
    float ls = 0.f;
    for (int e = d; e < C; e += 32) ls += __expf(t_lds[e*9 + h] - newm);
    #pragma unroll
    for (int off = 16; off >= 1; off >>= 1) ls += __shfl_xor(ls, off);
    const float scale = __expf(m - newm);   // first chunk: exp(-inf)=0
    s = s*scale + ls;
    m = newm;
    acc *= scale;
    // aggregate: coalesced 1KB gather of feat[src] per edge, 4-way unrolled for MLP
    int e = 0;
    for (; e + 4 <= C; e += 4){
      float f0 = feat[(size_t)srcs[e+0]*FDIM + tid];
      float f1 = feat[(size_t)srcs[e+1]*FDIM + tid];
      float f2 = feat[(size_t)srcs[e+2]*FDIM + tid];
      float f3 = feat[(size_t)srcs[e+3]*FDIM + tid];
      float w0 = __expf(t_lds[(e+0)*9 + h] - m);
      float w1 = __expf(t_lds[(e+1)*9 + h] - m);
      float w2 = __expf(t_lds[(e+2)*9 + h] - m);
      float w3 = __expf(t_lds[(e+3)*9 + h] - m);
      acc = fmaf(w0, f0, acc);
      acc = fmaf(w1, f1, acc);
      acc = fmaf(w2, f2, acc);
      acc = fmaf(w3, f3, acc);
    }
    for (; e < C; e++){
      float f0 = feat[(size_t)srcs[e]*FDIM + tid];
      float w0 = __expf(t_lds[e*9 + h] - m);
      acc = fmaf(w0, f0, acc);
    }
    __syncthreads();
  }

  float val = (end > start) ? (acc / s) : 0.f;
  val += bias[tid];
  if (RELU_MEAN) val = fmaxf(val, 0.f);
  red[tid] = val;
  __syncthreads();
  if (tid < 32){
    float sum = 0.f;
    #pragma unroll
    for (int hh = 0; hh < 8; hh++) sum += red[hh*32 + tid];
    sum *= 0.125f;   // mean over heads
    outp[(size_t)n*32 + tid] = sum;
  }
}

extern "C" void kernel_launch(void* const* d_in, const int* in_sizes, int n_in,
                              void* d_out, int out_size, void* d_ws, size_t ws_size,
                              hipStream_t stream)
{
  const float* x   = (const float*)d_in[0];
  const int*   src = (const int*)  d_in[1];
  const int*   dst = (const int*)  d_in[2];
  const float* W1  = (const float*)d_in[3];
  const float* al1 = (const float*)d_in[4];
  const float* ar1 = (const float*)d_in[5];
  const float* b1  = (const float*)d_in[6];
  const float* W2  = (const float*)d_in[7];
  const float* al2 = (const float*)d_in[8];
  const float* ar2 = (const float*)d_in[9];
  const float* b2  = (const float*)d_in[10];
  (void)in_sizes; (void)n_in; (void)out_size; (void)ws_size;

  size_t o = 0;
  char* base = (char*)d_ws;
  auto take = [&](size_t bytes) -> char* {
    char* p = base + o;
    o += (bytes + 255) & ~(size_t)255;
    return p;
  };
  float* feat   = (float*)take((size_t)N_NODES*FDIM*4);
  float* el     = (float*)take((size_t)N_NODES*NHEAD*4);
  float* er     = (float*)take((size_t)N_NODES*NHEAD*4);
  float* hbuf   = (float*)take((size_t)N_NODES*F_HID*4);
  int*   cnt    = (int*)  take((size_t)N_NODES*4);
  int*   rowptr = (int*)  take((size_t)(N_NODES+1)*4);
  int*   fillp  = (int*)  take((size_t)N_NODES*4);
  int*   colb   = (int*)  take((size_t)N_EDGES*4);

  // CSR by dst (shared by both layers)
  zero_kernel<<<(N_NODES+255)/256, 256, 0, stream>>>(cnt, N_NODES);
  hist_kernel<<<(N_EDGES+255)/256, 256, 0, stream>>>(dst, cnt, N_EDGES);
  scan_kernel<<<1, 1024, 0, stream>>>(cnt, rowptr, fillp, N_NODES);
  fill_kernel<<<(N_EDGES+255)/256, 256, 0, stream>>>(src, dst, fillp, colb, N_EDGES);

  // layer 1
  gemm_aux_kernel<F_IN><<<N_NODES/8, 256, 0, stream>>>(x, W1, al1, ar1, feat, el, er);
  edge_agg_kernel<1><<<N_NODES, 256, 0, stream>>>(feat, el, er, rowptr, colb, b1, hbuf);

  // layer 2
  gemm_aux_kernel<F_HID><<<N_NODES/8, 256, 0, stream>>>(hbuf, W2, al2, ar2, feat, el, er);
  edge_agg_kernel<0><<<N_NODES, 256, 0, stream>>>(feat, el, er, rowptr, colb, b2, (float*)d_out);
}

// Round 3
// 311.708 us; speedup vs baseline: 1.0182x; 1.0182x over previous
//
#include <hip/hip_runtime.h>
#include <hip/hip_bf16.h>

#define N_NODES 20000
#define N_EDGES 320000
#define F_IN    128
#define F_HID   32
#define NHEAD   8
#define FDIM    256   // NHEAD * D for both layers

typedef __hip_bfloat16 bf16;

// ---------------- CSR build ----------------
__global__ void zero_kernel(int* __restrict__ p, int n){
  int i = blockIdx.x*256 + threadIdx.x;
  if (i < n) p[i] = 0;
}

__global__ void hist_kernel(const int* __restrict__ dst, int* __restrict__ cnt, int e){
  int i = blockIdx.x*256 + threadIdx.x;
  if (i < e) atomicAdd(&cnt[dst[i]], 1);
}

__global__ __launch_bounds__(1024) void scan_kernel(
    const int* __restrict__ cnt, int* __restrict__ rowptr,
    int* __restrict__ fillp, int n)
{
  __shared__ int wsum[16];
  __shared__ int carry_s;
  const int tid = threadIdx.x;
  if (tid == 0) carry_s = 0;
  __syncthreads();
  for (int base = 0; base < n; base += 1024){
    const int i = base + tid;
    const int v = (i < n) ? cnt[i] : 0;
    const int lane = tid & 63;
    const int w = tid >> 6;
    int sc = v;
    #pragma unroll
    for (int o = 1; o < 64; o <<= 1){
      int t = __shfl_up(sc, o);
      if (lane >= o) sc += t;
    }
    if (lane == 63) wsum[w] = sc;
    const int c = carry_s;           // read before this iter's update
    __syncthreads();
    if (tid < 16){
      int sv = wsum[tid];
      #pragma unroll
      for (int o = 1; o < 16; o <<= 1){
        int t = __shfl_up(sv, o);
        if (tid >= o) sv += t;
      }
      wsum[tid] = sv;                // inclusive scan of wave sums
    }
    __syncthreads();
    const int woff = (w > 0) ? wsum[w-1] : 0;
    const int excl = sc + woff + c - v;
    if (i < n){ rowptr[i] = excl; fillp[i] = excl; }
    __syncthreads();
    if (tid == 1023) carry_s = c + wsum[15];
    __syncthreads();
  }
  if (tid == 0) rowptr[n] = carry_s;
}

__global__ void fill_kernel(const int* __restrict__ src, const int* __restrict__ dst,
                            int* __restrict__ fillp, int* __restrict__ col, int e){
  int i = blockIdx.x*256 + threadIdx.x;
  if (i < e){
    int d = dst[i];
    int p = atomicAdd(&fillp[d], 1);
    col[p] = src[i];
  }
}

// ---------------- feat = x @ W ; el/er = head-dot with al/ar ----------------
// block = 256 threads (one thread per output column), 8 nodes per block.
// feat stored bf16 (halves gather traffic downstream); el/er from fp32 accs.
template<int K>
__global__ __launch_bounds__(256) void gemm_aux_kernel(
    const float* __restrict__ x, const float* __restrict__ W,
    const float* __restrict__ al, const float* __restrict__ ar,
    bf16* __restrict__ feat, float* __restrict__ el, float* __restrict__ er)
{
  const int tid = threadIdx.x;
  const int n0  = blockIdx.x * 8;
  __shared__ float xl[8 * K];
  #pragma unroll
  for (int i = tid; i < (8*K)/4; i += 256){
    ((float4*)xl)[i] = ((const float4*)(x + (size_t)n0*K))[i];
  }
  __syncthreads();
  float acc[8] = {0.f,0.f,0.f,0.f,0.f,0.f,0.f,0.f};
  for (int k = 0; k < K; k += 4){
    float w0 = W[(k+0)*FDIM + tid];
    float w1 = W[(k+1)*FDIM + tid];
    float w2 = W[(k+2)*FDIM + tid];
    float w3 = W[(k+3)*FDIM + tid];
    #pragma unroll
    for (int nn = 0; nn < 8; nn++){
      float4 xv = *(const float4*)&xl[nn*K + k];   // wave-uniform broadcast read
      acc[nn] = fmaf(xv.x, w0, acc[nn]);
      acc[nn] = fmaf(xv.y, w1, acc[nn]);
      acc[nn] = fmaf(xv.z, w2, acc[nn]);
      acc[nn] = fmaf(xv.w, w3, acc[nn]);
    }
  }
  const float alv = al[tid];
  const float arv = ar[tid];
  #pragma unroll
  for (int nn = 0; nn < 8; nn++){
    const int nidx = n0 + nn;
    feat[(size_t)nidx*FDIM + tid] = __float2bfloat16(acc[nn]);
    float e_l = acc[nn] * alv;
    float e_r = acc[nn] * arv;
    #pragma unroll
    for (int off = 16; off >= 1; off >>= 1){
      e_l += __shfl_xor(e_l, off);   // stays within the 32-lane head group
      e_r += __shfl_xor(e_r, off);
    }
    if ((tid & 31) == 0){
      el[nidx*NHEAD + (tid >> 5)] = e_l;
      er[nidx*NHEAD + (tid >> 5)] = e_r;
    }
  }
}

// ---------------- per-dst-node edge softmax + aggregate ----------------
// block = 256 threads: thread = (h = tid>>5, d = tid&31). One block per node.
template<int RELU_MEAN>
__global__ __launch_bounds__(256) void edge_agg_kernel(
    const bf16* __restrict__ feat, const float* __restrict__ el,
    const float* __restrict__ er, const int* __restrict__ rowptr,
    const int* __restrict__ col, const float* __restrict__ bias,
    float* __restrict__ outp)
{
  const int n   = blockIdx.x;
  const int tid = threadIdx.x;
  const int h   = tid >> 5;
  const int d   = tid & 31;
  __shared__ float t_lds[128*9];   // stride 9: conflict-free strided access
  __shared__ int   srcs[128];
  __shared__ float er_lds[NHEAD];
  __shared__ float red[256];
  const int start = rowptr[n], end = rowptr[n+1];
  if (tid < NHEAD) er_lds[tid] = er[n*NHEAD + tid];
  __syncthreads();

  float m = -INFINITY, s = 0.f, acc = 0.f;
  for (int cs = start; cs < end; cs += 128){
    const int rem = end - cs;
    const int C = rem < 128 ? rem : 128;
    if (tid < C){
      const int sidx = col[cs + tid];
      srcs[tid] = sidx;
      const float4* e4 = (const float4*)(el + (size_t)sidx*NHEAD);
      float4 a = e4[0], bq = e4[1];
      float ev[8] = {a.x, a.y, a.z, a.w, bq.x, bq.y, bq.z, bq.w};
      #pragma unroll
      for (int hh = 0; hh < 8; hh++){
        float v = ev[hh] + er_lds[hh];
        t_lds[tid*9 + hh] = (v > 0.f) ? v : 0.2f*v;   // leaky_relu(0.2)
      }
    }
    __syncthreads();
    // chunk max per head (32-lane head group covers all C edges)
    float lm = -INFINITY;
    for (int e = d; e < C; e += 32) lm = fmaxf(lm, t_lds[e*9 + h]);
    #pragma unroll
    for (int off = 16; off >= 1; off >>= 1) lm = fmaxf(lm, __shfl_xor(lm, off));
    const float newm = fmaxf(m, lm);
    // denominator pass; store exp(t - newm) back in place (each slot touched
    // by exactly the thread that reads it — no intra-pass hazard)
    float ls = 0.f;
    for (int e = d; e < C; e += 32){
      float ex = __expf(t_lds[e*9 + h] - newm);
      t_lds[e*9 + h] = ex;
      ls += ex;
    }
    #pragma unroll
    for (int off = 16; off >= 1; off >>= 1) ls += __shfl_xor(ls, off);
    const float scale = __expf(m - newm);   // first chunk: exp(-inf)=0
    s = s*scale + ls;
    m = newm;
    acc *= scale;
    __syncthreads();   // exp weights visible to all heads' aggregate reads
    // aggregate: bf16 gather of feat[src] (512B/edge), weight from LDS
    int e = 0;
    for (; e + 4 <= C; e += 4){
      float f0 = __bfloat162float(feat[(size_t)srcs[e+0]*FDIM + tid]);
      float f1 = __bfloat162float(feat[(size_t)srcs[e+1]*FDIM + tid]);
      float f2 = __bfloat162float(feat[(size_t)srcs[e+2]*FDIM + tid]);
      float f3 = __bfloat162float(feat[(size_t)srcs[e+3]*FDIM + tid]);
      float w0 = t_lds[(e+0)*9 + h];
      float w1 = t_lds[(e+1)*9 + h];
      float w2 = t_lds[(e+2)*9 + h];
      float w3 = t_lds[(e+3)*9 + h];
      acc = fmaf(w0, f0, acc);
      acc = fmaf(w1, f1, acc);
      acc = fmaf(w2, f2, acc);
      acc = fmaf(w3, f3, acc);
    }
    for (; e < C; e++){
      float f0 = __bfloat162float(feat[(size_t)srcs[e]*FDIM + tid]);
      acc = fmaf(t_lds[e*9 + h], f0, acc);
    }
    __syncthreads();
  }

  float val = (end > start) ? (acc / s) : 0.f;
  val += bias[tid];
  if (RELU_MEAN) val = fmaxf(val, 0.f);
  red[tid] = val;
  __syncthreads();
  if (tid < 32){
    float sum = 0.f;
    #pragma unroll
    for (int hh = 0; hh < 8; hh++) sum += red[hh*32 + tid];
    sum *= 0.125f;   // mean over heads
    outp[(size_t)n*32 + tid] = sum;
  }
}

extern "C" void kernel_launch(void* const* d_in, const int* in_sizes, int n_in,
                              void* d_out, int out_size, void* d_ws, size_t ws_size,
                              hipStream_t stream)
{
  const float* x   = (const float*)d_in[0];
  const int*   src = (const int*)  d_in[1];
  const int*   dst = (const int*)  d_in[2];
  const float* W1  = (const float*)d_in[3];
  const float* al1 = (const float*)d_in[4];
  const float* ar1 = (const float*)d_in[5];
  const float* b1  = (const float*)d_in[6];
  const float* W2  = (const float*)d_in[7];
  const float* al2 = (const float*)d_in[8];
  const float* ar2 = (const float*)d_in[9];
  const float* b2  = (const float*)d_in[10];
  (void)in_sizes; (void)n_in; (void)out_size; (void)ws_size;

  size_t o = 0;
  char* base = (char*)d_ws;
  auto take = [&](size_t bytes) -> char* {
    char* p = base + o;
    o += (bytes + 255) & ~(size_t)255;
    return p;
  };
  bf16*  feat   = (bf16*) take((size_t)N_NODES*FDIM*2);
  float* el     = (float*)take((size_t)N_NODES*NHEAD*4);
  float* er     = (float*)take((size_t)N_NODES*NHEAD*4);
  float* hbuf   = (float*)take((size_t)N_NODES*F_HID*4);
  int*   cnt    = (int*)  take((size_t)N_NODES*4);
  int*   rowptr = (int*)  take((size_t)(N_NODES+1)*4);
  int*   fillp  = (int*)  take((size_t)N_NODES*4);
  int*   colb   = (int*)  take((size_t)N_EDGES*4);

  // CSR by dst (shared by both layers)
  zero_kernel<<<(N_NODES+255)/256, 256, 0, stream>>>(cnt, N_NODES);
  hist_kernel<<<(N_EDGES+255)/256, 256, 0, stream>>>(dst, cnt, N_EDGES);
  scan_kernel<<<1, 1024, 0, stream>>>(cnt, rowptr, fillp, N_NODES);
  fill_kernel<<<(N_EDGES+255)/256, 256, 0, stream>>>(src, dst, fillp, colb, N_EDGES);

  // layer 1
  gemm_aux_kernel<F_IN><<<N_NODES/8, 256, 0, stream>>>(x, W1, al1, ar1, feat, el, er);
  edge_agg_kernel<1><<<N_NODES, 256, 0, stream>>>(feat, el, er, rowptr, colb, b1, hbuf);

  // layer 2
  gemm_aux_kernel<F_HID><<<N_NODES/8, 256, 0, stream>>>(hbuf, W2, al2, ar2, feat, el, er);
  edge_agg_kernel<0><<<N_NODES, 256, 0, stream>>>(feat, el, er, rowptr, colb, b2, (float*)d_out);
}